// Round 3
// baseline (410.604 us; speedup 1.0000x reference)
//
#include <hip/hip_runtime.h>
#include <hip/hip_bf16.h>

#define N_NODES 100000
#define NFEA    128
#define HDIM    64
#define E_ORIG  1600000
#define E_CAND  800000
#define E_TOT   2400000

// flat f32 output offsets (elements), reference return order
#define OFF_REPS 0
#define OFF_PRED 6400000
#define OFF_TEI  8000000
#define OFF_EI   12800000

// workspace layout (bytes)
#define WS_FLAGS_OFF 0
#define WS_REPS_OFF  256
#define WS_REPS_BYTES (N_NODES * HDIM * 2)   // 12.8 MB bf16 reps
#define WS_NEED (WS_REPS_OFF + WS_REPS_BYTES)

typedef unsigned int u32;
typedef unsigned short u16;
typedef unsigned long long u64;

__device__ __forceinline__ float blo(u32 u) { return __uint_as_float(u << 16); }
__device__ __forceinline__ float bhi(u32 u) { return __uint_as_float(u & 0xFFFF0000u); }

// f32 -> bf16 bits, round-to-nearest-even
__device__ __forceinline__ u16 f_to_bf16(float f) {
    u32 x = __float_as_uint(f);
    return (u16)((x + 0x7FFFu + ((x >> 16) & 1u)) >> 16);
}
__device__ __forceinline__ float bf16_round(float f) {
    return __uint_as_float(((u32)f_to_bf16(f)) << 16);
}

template <bool BF16>
__device__ __forceinline__ void load4f(const void* p, int off, float* o) {
    if (BF16) {
        uint2 u = *(const uint2*)((const u16*)p + off);
        o[0] = blo(u.x); o[1] = bhi(u.x); o[2] = blo(u.y); o[3] = bhi(u.y);
    } else {
        float4 v = *(const float4*)((const float*)p + off);
        o[0] = v.x; o[1] = v.y; o[2] = v.z; o[3] = v.w;
    }
}

// ---------------------------------------------------------------------------
// Kernel 0: dtype detection -> flags in ws.  flags[0]=feats bf16,
// flags[1]=eidx int64, flags[2]=pidx int64.
// ---------------------------------------------------------------------------
__global__ void detect_kernel(const void* __restrict__ feats,
                              const int* __restrict__ eidx,
                              const int* __restrict__ pidx,
                              int* __restrict__ flags)
{
    int lane = threadIdx.x;  // 64 threads
    u32 w = ((const u32*)feats)[lane];
    float lowf = blo(w);
    bool plaus = (lowf == lowf) && (fabsf(lowf) > 0.001f) && (fabsf(lowf) < 64.0f);
    bool isbf16 = __popcll(__ballot(plaus)) >= 32;
    bool e64 = (__ballot(eidx[lane] != 0) & 0xAAAAAAAAAAAAAAAAull) == 0ull;
    bool p64 = (__ballot(pidx[lane] != 0) & 0xAAAAAAAAAAAAAAAAull) == 0ull;
    if (lane == 0) { flags[0] = isbf16; flags[1] = e64; flags[2] = p64; }
}

// ---------------------------------------------------------------------------
// Kernel 1: reps = relu(feat @ W1 + b1) @ W2 + b2.
// Writes f32 reps to d_out and bf16 reps to ws (for the edge gather).
// 64 rows/block, 256 threads, 4x4 reg tile per lane. Dtype-specialized body.
// ---------------------------------------------------------------------------
template <bool BF16>
__device__ __forceinline__ void mlp_body(const void* __restrict__ feats,
                                         const void* __restrict__ W1,
                                         const void* __restrict__ b1,
                                         const void* __restrict__ W2,
                                         const void* __restrict__ b2,
                                         float* __restrict__ out_reps,
                                         u16* __restrict__ ws_reps)
{
    __shared__ float featLds[64][NFEA + 4];
    __shared__ float hLds[64][HDIM + 4];

    const int t       = threadIdx.x;
    const int lane    = t & 63;
    const int wv      = t >> 6;
    const int rowBase = blockIdx.x * 64;

    for (int idx = t; idx < 64 * 32; idx += 256) {
        int r = idx >> 5, q = idx & 31;
        int gr = rowBase + r;
        float v0 = 0.f, v1 = 0.f, v2 = 0.f, v3 = 0.f;
        if (gr < N_NODES) {
            if (BF16) {
                uint2 u = ((const uint2*)feats)[gr * 32 + q];
                v0 = blo(u.x); v1 = bhi(u.x); v2 = blo(u.y); v3 = bhi(u.y);
            } else {
                float4 v = ((const float4*)feats)[gr * 32 + q];
                v0 = v.x; v1 = v.y; v2 = v.z; v3 = v.w;
            }
        }
        featLds[r][q * 4 + 0] = v0; featLds[r][q * 4 + 1] = v1;
        featLds[r][q * 4 + 2] = v2; featLds[r][q * 4 + 3] = v3;
    }
    __syncthreads();

    const int r0 = wv * 16 + (lane >> 4) * 4;
    const int c0 = (lane & 15) * 4;

    // phase A: h = relu(feat @ W1 + b1)
    float acc[4][4];
    {
        float bb[4];
        load4f<BF16>(b1, c0, bb);
        #pragma unroll
        for (int r = 0; r < 4; ++r)
            #pragma unroll
            for (int c = 0; c < 4; ++c) acc[r][c] = bb[c];
    }
    for (int kk = 0; kk < NFEA; kk += 4) {
        float fr[4][4];
        #pragma unroll
        for (int r = 0; r < 4; ++r) {
            float4 v = *(const float4*)&featLds[r0 + r][kk];
            fr[r][0] = v.x; fr[r][1] = v.y; fr[r][2] = v.z; fr[r][3] = v.w;
        }
        float wr[4][4];
        #pragma unroll
        for (int q = 0; q < 4; ++q) load4f<BF16>(W1, (kk + q) * HDIM + c0, wr[q]);
        #pragma unroll
        for (int q = 0; q < 4; ++q)
            #pragma unroll
            for (int r = 0; r < 4; ++r)
                #pragma unroll
                for (int c = 0; c < 4; ++c)
                    acc[r][c] = fmaf(fr[r][q], wr[q][c], acc[r][c]);
    }
    #pragma unroll
    for (int r = 0; r < 4; ++r) {
        float4 hv;
        hv.x = fmaxf(acc[r][0], 0.f); hv.y = fmaxf(acc[r][1], 0.f);
        hv.z = fmaxf(acc[r][2], 0.f); hv.w = fmaxf(acc[r][3], 0.f);
        *(float4*)&hLds[r0 + r][c0] = hv;
    }
    __syncthreads();

    // phase B: reps = h @ W2 + b2
    float acc2[4][4];
    {
        float bb[4];
        load4f<BF16>(b2, c0, bb);
        #pragma unroll
        for (int r = 0; r < 4; ++r)
            #pragma unroll
            for (int c = 0; c < 4; ++c) acc2[r][c] = bb[c];
    }
    for (int kk = 0; kk < HDIM; kk += 4) {
        float fr[4][4];
        #pragma unroll
        for (int r = 0; r < 4; ++r) {
            float4 v = *(const float4*)&hLds[r0 + r][kk];
            fr[r][0] = v.x; fr[r][1] = v.y; fr[r][2] = v.z; fr[r][3] = v.w;
        }
        float wr[4][4];
        #pragma unroll
        for (int q = 0; q < 4; ++q) load4f<BF16>(W2, (kk + q) * HDIM + c0, wr[q]);
        #pragma unroll
        for (int q = 0; q < 4; ++q)
            #pragma unroll
            for (int r = 0; r < 4; ++r)
                #pragma unroll
                for (int c = 0; c < 4; ++c)
                    acc2[r][c] = fmaf(fr[r][q], wr[q][c], acc2[r][c]);
    }

    #pragma unroll
    for (int r = 0; r < 4; ++r) {
        int gr = rowBase + r0 + r;
        if (gr < N_NODES) {
            float4 v;
            v.x = acc2[r][0]; v.y = acc2[r][1]; v.z = acc2[r][2]; v.w = acc2[r][3];
            *(float4*)(out_reps + (size_t)gr * HDIM + c0) = v;
            if (ws_reps) {
                uint2 pk;
                pk.x = (u32)f_to_bf16(v.x) | ((u32)f_to_bf16(v.y) << 16);
                pk.y = (u32)f_to_bf16(v.z) | ((u32)f_to_bf16(v.w) << 16);
                *(uint2*)(ws_reps + (size_t)gr * HDIM + c0) = pk;
            }
        }
    }
}

__global__ void __launch_bounds__(256)
mlp_kernel(const void* __restrict__ feats,
           const void* __restrict__ W1, const void* __restrict__ b1,
           const void* __restrict__ W2, const void* __restrict__ b2,
           float* __restrict__ out_reps, u16* __restrict__ ws_reps,
           const int* __restrict__ flags)
{
    if (flags[0]) mlp_body<true >(feats, W1, b1, W2, b2, out_reps, ws_reps);
    else          mlp_body<false>(feats, W1, b1, W2, b2, out_reps, ws_reps);
}

// ---------------------------------------------------------------------------
// Kernel 2a: edge dots from bf16 ws reps (128 B/row = 1 cacheline).
// 8 lanes/edge.
// ---------------------------------------------------------------------------
__global__ void __launch_bounds__(256)
edge_dot_bf16_kernel(const int* __restrict__ eidx,
                     const u16* __restrict__ reps,
                     float* __restrict__ out_pred,
                     const int* __restrict__ flags)
{
    const bool is64 = flags[1] != 0;
    int t = blockIdx.x * 256 + threadIdx.x;   // exactly E_ORIG*8 threads
    int e = t >> 3;
    int g = t & 7;
    int s = is64 ? eidx[2 * (size_t)e]            : eidx[e];
    int d = is64 ? eidx[2 * ((size_t)E_ORIG + e)] : eidx[E_ORIG + e];
    uint4 a = *((const uint4*)(reps + (size_t)s * HDIM) + g);
    uint4 b = *((const uint4*)(reps + (size_t)d * HDIM) + g);
    float dot;
    dot = blo(a.x) * blo(b.x);
    dot = fmaf(bhi(a.x), bhi(b.x), dot);
    dot = fmaf(blo(a.y), blo(b.y), dot);
    dot = fmaf(bhi(a.y), bhi(b.y), dot);
    dot = fmaf(blo(a.z), blo(b.z), dot);
    dot = fmaf(bhi(a.z), bhi(b.z), dot);
    dot = fmaf(blo(a.w), blo(b.w), dot);
    dot = fmaf(bhi(a.w), bhi(b.w), dot);
    dot += __shfl_xor(dot, 1);
    dot += __shfl_xor(dot, 2);
    dot += __shfl_xor(dot, 4);
    if (g == 0) out_pred[e] = fmaxf(dot, 0.f);
}

// Kernel 2b: fallback — f32 gather from d_out reps (if ws too small).
__global__ void __launch_bounds__(256)
edge_dot_f32_kernel(const int* __restrict__ eidx,
                    const float* __restrict__ reps,
                    float* __restrict__ out_pred,
                    const int* __restrict__ flags)
{
    const bool is64 = flags[1] != 0;
    int t = blockIdx.x * 256 + threadIdx.x;   // exactly E_ORIG*16 threads
    int e = t >> 4;
    int g = t & 15;
    int s = is64 ? eidx[2 * (size_t)e]            : eidx[e];
    int d = is64 ? eidx[2 * ((size_t)E_ORIG + e)] : eidx[E_ORIG + e];
    float4 a = *((const float4*)(reps + (size_t)s * HDIM) + g);
    float4 b = *((const float4*)(reps + (size_t)d * HDIM) + g);
    float dot = a.x * b.x;
    dot = fmaf(a.y, b.y, dot);
    dot = fmaf(a.z, b.z, dot);
    dot = fmaf(a.w, b.w, dot);
    dot += __shfl_xor(dot, 1);
    dot += __shfl_xor(dot, 2);
    dot += __shfl_xor(dot, 4);
    dot += __shfl_xor(dot, 8);
    if (g == 0) out_pred[e] = fmaxf(dot, 0.f);
}

// ---------------------------------------------------------------------------
// Kernel 3: index copies as f32 (bf16-rounded). 4 elems/thread, 16B accesses.
// packs: tei = 1,200,000 then ei = 800,000 (both segments 4-aligned).
// ---------------------------------------------------------------------------
__global__ void __launch_bounds__(256)
idx_out_kernel(const int* __restrict__ eidx, const int* __restrict__ pidx,
               float* __restrict__ out_tei, float* __restrict__ out_ei,
               const int* __restrict__ flags)
{
    const bool e64 = flags[1] != 0;
    const bool p64 = flags[2] != 0;
    int p = blockIdx.x * 256 + threadIdx.x;
    if (p >= (2 * E_TOT + 2 * E_ORIG) / 4) return;

    const int* src; size_t base; bool s64; float* dst; int o0;
    if (p < (2 * E_TOT) / 4) {
        int i0 = p * 4;
        int row = (i0 >= E_TOT) ? 1 : 0;
        int c = i0 - row * E_TOT;
        if (c < E_ORIG) { src = eidx; base = (size_t)row * E_ORIG + c; s64 = e64; }
        else            { src = pidx; base = (size_t)row * E_CAND + (c - E_ORIG); s64 = p64; }
        dst = out_tei; o0 = i0;
    } else {
        int j0 = (p - (2 * E_TOT) / 4) * 4;
        src = eidx; base = (size_t)j0; s64 = e64; dst = out_ei; o0 = j0;
    }

    int v0, v1, v2, v3;
    if (s64) {
        const long long* s8 = (const long long*)src + base;
        ulonglong2 a = *(const ulonglong2*)s8;
        ulonglong2 b = *((const ulonglong2*)s8 + 1);
        v0 = (int)a.x; v1 = (int)a.y; v2 = (int)b.x; v3 = (int)b.y;
    } else {
        int4 a = *(const int4*)(src + base);
        v0 = a.x; v1 = a.y; v2 = a.z; v3 = a.w;
    }
    float4 o;
    o.x = bf16_round((float)v0); o.y = bf16_round((float)v1);
    o.z = bf16_round((float)v2); o.w = bf16_round((float)v3);
    *(float4*)(dst + o0) = o;
}

extern "C" void kernel_launch(void* const* d_in, const int* in_sizes, int n_in,
                              void* d_out, int out_size, void* d_ws, size_t ws_size,
                              hipStream_t stream) {
    const void* feats = d_in[0];
    const int*  eidx  = (const int*)d_in[1];
    const int*  pidx  = (const int*)d_in[2];
    const void* W1    = d_in[3];
    const void* b1    = d_in[4];
    const void* W2    = d_in[5];
    const void* b2    = d_in[6];

    float* out      = (float*)d_out;
    float* out_reps = out + OFF_REPS;
    float* out_pred = out + OFF_PRED;
    float* out_tei  = out + OFF_TEI;
    float* out_ei   = out + OFF_EI;

    int* flags   = (int*)((char*)d_ws + WS_FLAGS_OFF);
    u16* ws_reps = (u16*)((char*)d_ws + WS_REPS_OFF);
    const bool use_bf16_gather = (ws_size >= WS_NEED);

    // 0) dtype detection (1 wave)
    detect_kernel<<<1, 64, 0, stream>>>(feats, eidx, pidx, flags);

    // 1) MLP (writes f32 reps to out, bf16 reps to ws)
    int mlp_blocks = (N_NODES + 63) / 64;        // 1563
    mlp_kernel<<<mlp_blocks, 256, 0, stream>>>(feats, W1, b1, W2, b2, out_reps,
                                               use_bf16_gather ? ws_reps : (u16*)nullptr,
                                               flags);

    // 2) edge dots for orig edges
    if (use_bf16_gather) {
        int blocks = (E_ORIG * 8) / 256;         // 50000
        edge_dot_bf16_kernel<<<blocks, 256, 0, stream>>>(eidx, ws_reps, out_pred, flags);
    } else {
        int blocks = (E_ORIG * 16) / 256;        // 100000
        edge_dot_f32_kernel<<<blocks, 256, 0, stream>>>(eidx, out_reps, out_pred, flags);
    }

    // 3) index copies
    int idx_packs = (2 * E_TOT + 2 * E_ORIG) / 4;   // 2,000,000
    int idx_blocks = (idx_packs + 255) / 256;       // 7813
    idx_out_kernel<<<idx_blocks, 256, 0, stream>>>(eidx, pidx, out_tei, out_ei, flags);
}

// Round 5
// 259.220 us; speedup vs baseline: 1.5840x; 1.5840x over previous
//
#include <hip/hip_runtime.h>
#include <hip/hip_bf16.h>

#define N_NODES 100000
#define NFEA    128
#define HDIM    64
#define E_ORIG  1600000
#define E_CAND  800000
#define E_TOT   2400000

// flat f32 output offsets (elements), reference return order
#define OFF_REPS 0
#define OFF_PRED 6400000
#define OFF_TEI  8000000
#define OFF_EI   12800000

// workspace layout (bytes)
#define WS_FLAGS_OFF 0
#define WS_REPS_OFF  256
#define WS_REPS_BYTES (N_NODES * HDIM * 2)   // 12.8 MB bf16 reps
#define WS_NEED (WS_REPS_OFF + WS_REPS_BYTES)

typedef unsigned int u32;
typedef unsigned short u16;

__device__ __forceinline__ float blo(u32 u) { return __uint_as_float(u << 16); }
__device__ __forceinline__ float bhi(u32 u) { return __uint_as_float(u & 0xFFFF0000u); }

// f32 -> bf16 bits, round-to-nearest-even
__device__ __forceinline__ u16 f_to_bf16(float f) {
    u32 x = __float_as_uint(f);
    return (u16)((x + 0x7FFFu + ((x >> 16) & 1u)) >> 16);
}
__device__ __forceinline__ float bf16_round(float f) {
    return __uint_as_float(((u32)f_to_bf16(f)) << 16);
}

template <bool BF16>
__device__ __forceinline__ void load4f(const void* p, int off, float* o) {
    if (BF16) {
        uint2 u = *(const uint2*)((const u16*)p + off);
        o[0] = blo(u.x); o[1] = bhi(u.x); o[2] = blo(u.y); o[3] = bhi(u.y);
    } else {
        float4 v = *(const float4*)((const float*)p + off);
        o[0] = v.x; o[1] = v.y; o[2] = v.z; o[3] = v.w;
    }
}

// ---------------------------------------------------------------------------
// Kernel 0: dtype detection -> flags in ws.  flags[0]=feats bf16,
// flags[1]=eidx int64, flags[2]=pidx int64.
// ---------------------------------------------------------------------------
__global__ void detect_kernel(const void* __restrict__ feats,
                              const int* __restrict__ eidx,
                              const int* __restrict__ pidx,
                              int* __restrict__ flags)
{
    int lane = threadIdx.x;  // 64 threads
    u32 w = ((const u32*)feats)[lane];
    float lowf = blo(w);
    bool plaus = (lowf == lowf) && (fabsf(lowf) > 0.001f) && (fabsf(lowf) < 64.0f);
    bool isbf16 = __popcll(__ballot(plaus)) >= 32;
    bool e64 = (__ballot(eidx[lane] != 0) & 0xAAAAAAAAAAAAAAAAull) == 0ull;
    bool p64 = (__ballot(pidx[lane] != 0) & 0xAAAAAAAAAAAAAAAAull) == 0ull;
    if (lane == 0) { flags[0] = isbf16; flags[1] = e64; flags[2] = p64; }
}

// ---------------------------------------------------------------------------
// MLP body: reps = relu(feat @ W1 + b1) @ W2 + b2.
// Writes f32 reps to d_out and bf16 reps to ws. 64 rows/block, 256 threads,
// 4x4 reg tile per lane. One instantiation per __global__ (one LDS block!).
// ---------------------------------------------------------------------------
template <bool BF16>
__device__ __forceinline__ void mlp_body(const void* __restrict__ feats,
                                         const void* __restrict__ W1,
                                         const void* __restrict__ b1,
                                         const void* __restrict__ W2,
                                         const void* __restrict__ b2,
                                         float* __restrict__ out_reps,
                                         u16* __restrict__ ws_reps)
{
    __shared__ float featLds[64][NFEA + 4];
    __shared__ float hLds[64][HDIM + 4];

    const int t       = threadIdx.x;
    const int lane    = t & 63;
    const int wv      = t >> 6;
    const int rowBase = blockIdx.x * 64;

    for (int idx = t; idx < 64 * 32; idx += 256) {
        int r = idx >> 5, q = idx & 31;
        int gr = rowBase + r;
        float v0 = 0.f, v1 = 0.f, v2 = 0.f, v3 = 0.f;
        if (gr < N_NODES) {
            if (BF16) {
                uint2 u = ((const uint2*)feats)[gr * 32 + q];
                v0 = blo(u.x); v1 = bhi(u.x); v2 = blo(u.y); v3 = bhi(u.y);
            } else {
                float4 v = ((const float4*)feats)[gr * 32 + q];
                v0 = v.x; v1 = v.y; v2 = v.z; v3 = v.w;
            }
        }
        featLds[r][q * 4 + 0] = v0; featLds[r][q * 4 + 1] = v1;
        featLds[r][q * 4 + 2] = v2; featLds[r][q * 4 + 3] = v3;
    }
    __syncthreads();

    const int r0 = wv * 16 + (lane >> 4) * 4;
    const int c0 = (lane & 15) * 4;

    // phase A: h = relu(feat @ W1 + b1)
    float acc[4][4];
    {
        float bb[4];
        load4f<BF16>(b1, c0, bb);
        #pragma unroll
        for (int r = 0; r < 4; ++r)
            #pragma unroll
            for (int c = 0; c < 4; ++c) acc[r][c] = bb[c];
    }
    for (int kk = 0; kk < NFEA; kk += 4) {
        float fr[4][4];
        #pragma unroll
        for (int r = 0; r < 4; ++r) {
            float4 v = *(const float4*)&featLds[r0 + r][kk];
            fr[r][0] = v.x; fr[r][1] = v.y; fr[r][2] = v.z; fr[r][3] = v.w;
        }
        float wr[4][4];
        #pragma unroll
        for (int q = 0; q < 4; ++q) load4f<BF16>(W1, (kk + q) * HDIM + c0, wr[q]);
        #pragma unroll
        for (int q = 0; q < 4; ++q)
            #pragma unroll
            for (int r = 0; r < 4; ++r)
                #pragma unroll
                for (int c = 0; c < 4; ++c)
                    acc[r][c] = fmaf(fr[r][q], wr[q][c], acc[r][c]);
    }
    #pragma unroll
    for (int r = 0; r < 4; ++r) {
        float4 hv;
        hv.x = fmaxf(acc[r][0], 0.f); hv.y = fmaxf(acc[r][1], 0.f);
        hv.z = fmaxf(acc[r][2], 0.f); hv.w = fmaxf(acc[r][3], 0.f);
        *(float4*)&hLds[r0 + r][c0] = hv;
    }
    __syncthreads();

    // phase B: reps = h @ W2 + b2
    float acc2[4][4];
    {
        float bb[4];
        load4f<BF16>(b2, c0, bb);
        #pragma unroll
        for (int r = 0; r < 4; ++r)
            #pragma unroll
            for (int c = 0; c < 4; ++c) acc2[r][c] = bb[c];
    }
    for (int kk = 0; kk < HDIM; kk += 4) {
        float fr[4][4];
        #pragma unroll
        for (int r = 0; r < 4; ++r) {
            float4 v = *(const float4*)&hLds[r0 + r][kk];
            fr[r][0] = v.x; fr[r][1] = v.y; fr[r][2] = v.z; fr[r][3] = v.w;
        }
        float wr[4][4];
        #pragma unroll
        for (int q = 0; q < 4; ++q) load4f<BF16>(W2, (kk + q) * HDIM + c0, wr[q]);
        #pragma unroll
        for (int q = 0; q < 4; ++q)
            #pragma unroll
            for (int r = 0; r < 4; ++r)
                #pragma unroll
                for (int c = 0; c < 4; ++c)
                    acc2[r][c] = fmaf(fr[r][q], wr[q][c], acc2[r][c]);
    }

    #pragma unroll
    for (int r = 0; r < 4; ++r) {
        int gr = rowBase + r0 + r;
        if (gr < N_NODES) {
            float4 v;
            v.x = acc2[r][0]; v.y = acc2[r][1]; v.z = acc2[r][2]; v.w = acc2[r][3];
            *(float4*)(out_reps + (size_t)gr * HDIM + c0) = v;
            uint2 pk;
            pk.x = (u32)f_to_bf16(v.x) | ((u32)f_to_bf16(v.y) << 16);
            pk.y = (u32)f_to_bf16(v.z) | ((u32)f_to_bf16(v.w) << 16);
            *(uint2*)(ws_reps + (size_t)gr * HDIM + c0) = pk;
        }
    }
}

// Two separate __global__ kernels -> one LDS block & clean regalloc each.
// The non-matching one early-exits on the device-side flag.
__global__ void __launch_bounds__(256)
mlp_f32_kernel(const void* __restrict__ feats,
               const void* __restrict__ W1, const void* __restrict__ b1,
               const void* __restrict__ W2, const void* __restrict__ b2,
               float* __restrict__ out_reps, u16* __restrict__ ws_reps,
               const int* __restrict__ flags)
{
    if (flags[0] != 0) return;   // inputs are bf16 -> wrong kernel, exit
    mlp_body<false>(feats, W1, b1, W2, b2, out_reps, ws_reps);
}

__global__ void __launch_bounds__(256)
mlp_bf16_kernel(const void* __restrict__ feats,
                const void* __restrict__ W1, const void* __restrict__ b1,
                const void* __restrict__ W2, const void* __restrict__ b2,
                float* __restrict__ out_reps, u16* __restrict__ ws_reps,
                const int* __restrict__ flags)
{
    if (flags[0] == 0) return;   // inputs are f32 -> wrong kernel, exit
    mlp_body<true>(feats, W1, b1, W2, b2, out_reps, ws_reps);
}

// ---------------------------------------------------------------------------
// Kernel 2: edge dots from bf16 ws reps (128 B/row = 1 cacheline).
// 8 lanes/edge, exactly E_ORIG*8 threads.
// ---------------------------------------------------------------------------
__global__ void __launch_bounds__(256)
edge_dot_bf16_kernel(const int* __restrict__ eidx,
                     const u16* __restrict__ reps,
                     float* __restrict__ out_pred,
                     const int* __restrict__ flags)
{
    const bool is64 = flags[1] != 0;
    int t = blockIdx.x * 256 + threadIdx.x;
    int e = t >> 3;
    int g = t & 7;
    int s = is64 ? eidx[2 * (size_t)e]            : eidx[e];
    int d = is64 ? eidx[2 * ((size_t)E_ORIG + e)] : eidx[E_ORIG + e];
    uint4 a = *((const uint4*)(reps + (size_t)s * HDIM) + g);
    uint4 b = *((const uint4*)(reps + (size_t)d * HDIM) + g);
    float dot;
    dot = blo(a.x) * blo(b.x);
    dot = fmaf(bhi(a.x), bhi(b.x), dot);
    dot = fmaf(blo(a.y), blo(b.y), dot);
    dot = fmaf(bhi(a.y), bhi(b.y), dot);
    dot = fmaf(blo(a.z), blo(b.z), dot);
    dot = fmaf(bhi(a.z), bhi(b.z), dot);
    dot = fmaf(blo(a.w), blo(b.w), dot);
    dot = fmaf(bhi(a.w), bhi(b.w), dot);
    dot += __shfl_xor(dot, 1);
    dot += __shfl_xor(dot, 2);
    dot += __shfl_xor(dot, 4);
    if (g == 0) out_pred[e] = fmaxf(dot, 0.f);
}

// ---------------------------------------------------------------------------
// Kernel 3: index copies as f32 (bf16-rounded). 4 elems/thread, 16B accesses.
// ---------------------------------------------------------------------------
__global__ void __launch_bounds__(256)
idx_out_kernel(const int* __restrict__ eidx, const int* __restrict__ pidx,
               float* __restrict__ out_tei, float* __restrict__ out_ei,
               const int* __restrict__ flags)
{
    const bool e64 = flags[1] != 0;
    const bool p64 = flags[2] != 0;
    int p = blockIdx.x * 256 + threadIdx.x;
    if (p >= (2 * E_TOT + 2 * E_ORIG) / 4) return;

    const int* src; size_t base; bool s64; float* dst; int o0;
    if (p < (2 * E_TOT) / 4) {
        int i0 = p * 4;
        int row = (i0 >= E_TOT) ? 1 : 0;
        int c = i0 - row * E_TOT;
        if (c < E_ORIG) { src = eidx; base = (size_t)row * E_ORIG + c; s64 = e64; }
        else            { src = pidx; base = (size_t)row * E_CAND + (c - E_ORIG); s64 = p64; }
        dst = out_tei; o0 = i0;
    } else {
        int j0 = (p - (2 * E_TOT) / 4) * 4;
        src = eidx; base = (size_t)j0; s64 = e64; dst = out_ei; o0 = j0;
    }

    int v0, v1, v2, v3;
    if (s64) {
        const long long* s8 = (const long long*)src + base;
        ulonglong2 a = *(const ulonglong2*)s8;
        ulonglong2 b = *((const ulonglong2*)s8 + 1);
        v0 = (int)a.x; v1 = (int)a.y; v2 = (int)b.x; v3 = (int)b.y;
    } else {
        int4 a = *(const int4*)(src + base);
        v0 = a.x; v1 = a.y; v2 = a.z; v3 = a.w;
    }
    float4 o;
    o.x = bf16_round((float)v0); o.y = bf16_round((float)v1);
    o.z = bf16_round((float)v2); o.w = bf16_round((float)v3);
    *(float4*)(dst + o0) = o;
}

extern "C" void kernel_launch(void* const* d_in, const int* in_sizes, int n_in,
                              void* d_out, int out_size, void* d_ws, size_t ws_size,
                              hipStream_t stream) {
    const void* feats = d_in[0];
    const int*  eidx  = (const int*)d_in[1];
    const int*  pidx  = (const int*)d_in[2];
    const void* W1    = d_in[3];
    const void* b1    = d_in[4];
    const void* W2    = d_in[5];
    const void* b2    = d_in[6];

    float* out      = (float*)d_out;
    float* out_reps = out + OFF_REPS;
    float* out_pred = out + OFF_PRED;
    float* out_tei  = out + OFF_TEI;
    float* out_ei   = out + OFF_EI;

    int* flags   = (int*)((char*)d_ws + WS_FLAGS_OFF);
    u16* ws_reps = (u16*)((char*)d_ws + WS_REPS_OFF);

    // 0) dtype detection (1 wave)
    detect_kernel<<<1, 64, 0, stream>>>(feats, eidx, pidx, flags);

    // 1) MLP — both specializations launched; exactly one does the work
    int mlp_blocks = (N_NODES + 63) / 64;        // 1563
    mlp_f32_kernel <<<mlp_blocks, 256, 0, stream>>>(feats, W1, b1, W2, b2,
                                                    out_reps, ws_reps, flags);
    mlp_bf16_kernel<<<mlp_blocks, 256, 0, stream>>>(feats, W1, b1, W2, b2,
                                                    out_reps, ws_reps, flags);

    // 2) edge dots for orig edges (bf16 gather, 1 cacheline per row)
    int dot_blocks = (E_ORIG * 8) / 256;         // 50000
    edge_dot_bf16_kernel<<<dot_blocks, 256, 0, stream>>>(eidx, ws_reps, out_pred, flags);

    // 3) index copies
    int idx_packs = (2 * E_TOT + 2 * E_ORIG) / 4;   // 2,000,000
    int idx_blocks = (idx_packs + 255) / 256;       // 7813
    idx_out_kernel<<<idx_blocks, 256, 0, stream>>>(eidx, pidx, out_tei, out_ei, flags);
}

// Round 6
// 215.841 us; speedup vs baseline: 1.9023x; 1.2010x over previous
//
#include <hip/hip_runtime.h>
#include <hip/hip_bf16.h>

#define N_NODES 100000
#define NFEA    128
#define HDIM    64
#define E_ORIG  1600000
#define E_CAND  800000
#define E_TOT   2400000

// flat f32 output offsets (elements), reference return order
#define OFF_REPS 0
#define OFF_PRED 6400000
#define OFF_TEI  8000000
#define OFF_EI   12800000

// workspace layout (bytes)
#define WS_FLAGS_OFF 0
#define WS_REPS_OFF  256
#define WS_REPS_BYTES (N_NODES * HDIM * 2)   // 12.8 MB bf16 reps

// mlp tiling
#define ROWS 32                   // rows per block (100000 = 32 * 3125)
#define FLDA (NFEA + 4)           // featLds row stride (floats), 16B-aligned
#define HLDA (HDIM + 4)           // hLds row stride (floats), 16B-aligned

typedef unsigned int u32;
typedef unsigned short u16;

__device__ __forceinline__ float blo(u32 u) { return __uint_as_float(u << 16); }
__device__ __forceinline__ float bhi(u32 u) { return __uint_as_float(u & 0xFFFF0000u); }

// f32 -> bf16 bits, round-to-nearest-even
__device__ __forceinline__ u16 f_to_bf16(float f) {
    u32 x = __float_as_uint(f);
    return (u16)((x + 0x7FFFu + ((x >> 16) & 1u)) >> 16);
}
__device__ __forceinline__ float bf16_round(float f) {
    return __uint_as_float(((u32)f_to_bf16(f)) << 16);
}

template <bool BF16>
__device__ __forceinline__ void load4f(const void* p, size_t off, float* o) {
    if (BF16) {
        uint2 u = *(const uint2*)((const u16*)p + off);
        o[0] = blo(u.x); o[1] = bhi(u.x); o[2] = blo(u.y); o[3] = bhi(u.y);
    } else {
        float4 v = *(const float4*)((const float*)p + off);
        o[0] = v.x; o[1] = v.y; o[2] = v.z; o[3] = v.w;
    }
}

// ---------------------------------------------------------------------------
// Kernel 0: dtype detection -> flags in ws.  flags[0]=feats bf16,
// flags[1]=eidx int64, flags[2]=pidx int64.
// ---------------------------------------------------------------------------
__global__ void detect_kernel(const void* __restrict__ feats,
                              const int* __restrict__ eidx,
                              const int* __restrict__ pidx,
                              int* __restrict__ flags)
{
    int lane = threadIdx.x;  // 64 threads
    u32 w = ((const u32*)feats)[lane];
    float lowf = blo(w);
    bool plaus = (lowf == lowf) && (fabsf(lowf) > 0.001f) && (fabsf(lowf) < 64.0f);
    bool isbf16 = __popcll(__ballot(plaus)) >= 32;
    bool e64 = (__ballot(eidx[lane] != 0) & 0xAAAAAAAAAAAAAAAAull) == 0ull;
    bool p64 = (__ballot(pidx[lane] != 0) & 0xAAAAAAAAAAAAAAAAull) == 0ull;
    if (lane == 0) { flags[0] = isbf16; flags[1] = e64; flags[2] = p64; }
}

// ---------------------------------------------------------------------------
// MLP: reps = relu(feat @ W1 + b1) @ W2 + b2.
// 32 rows/block, 256 threads (4 waves), 2 rows x 4 cols per lane.
// W1 staged in LDS for phase A; its region is REUSED for hLds + W2 in phase B
// (keeps total static LDS at 48.5 KB -> 3 blocks/CU, and the inner loops read
// only LDS so the compiler doesn't pipeline global loads into 252 VGPRs).
// ---------------------------------------------------------------------------
template <bool BF16>
__device__ __forceinline__ void mlp_body(const void* __restrict__ feats,
                                         const void* __restrict__ W1,
                                         const void* __restrict__ b1,
                                         const void* __restrict__ W2,
                                         const void* __restrict__ b2,
                                         float* __restrict__ out_reps,
                                         u16* __restrict__ ws_reps)
{
    __shared__ float smemA[NFEA * HDIM];      // 32768 B: sW1 | (hLds + sW2)
    __shared__ float smemB[ROWS * FLDA];      // 16896 B: featLds

    float* sW1     = smemA;                   // [128][64]
    float* hLds    = smemA;                   // [32][68]  (phase B)
    float* sW2     = smemA + ROWS * HLDA;     // [64][64]  (phase B), offset 8704 B
    float* featLds = smemB;                   // [32][132]

    const int t       = threadIdx.x;
    const int lane    = t & 63;
    const int wv      = t >> 6;
    const int rowBase = blockIdx.x * ROWS;

    // ---- stage W1 (2048 float4) and feat tile (1024 float4) ----
    for (int i = t; i < (NFEA * HDIM) / 4; i += 256) {
        float v[4]; load4f<BF16>(W1, (size_t)i * 4, v);
        *(float4*)&sW1[i * 4] = make_float4(v[0], v[1], v[2], v[3]);
    }
    for (int i = t; i < (ROWS * NFEA) / 4; i += 256) {
        int r = i >> 5, q = i & 31;
        float v[4]; load4f<BF16>(feats, (size_t)(rowBase + r) * NFEA + q * 4, v);
        *(float4*)&featLds[r * FLDA + q * 4] = make_float4(v[0], v[1], v[2], v[3]);
    }
    __syncthreads();

    const int r0 = wv * 8 + (lane >> 4) * 2;   // 2-row group
    const int c0 = (lane & 15) * 4;            // 4-col group

    // ---- phase A: h = relu(feat @ W1 + b1) ----
    float acc[2][4];
    {
        float bb[4]; load4f<BF16>(b1, c0, bb);
        #pragma unroll
        for (int r = 0; r < 2; ++r)
            #pragma unroll
            for (int c = 0; c < 4; ++c) acc[r][c] = bb[c];
    }
    #pragma unroll 2
    for (int kk = 0; kk < NFEA; kk += 4) {
        float fr[2][4], wr[4][4];
        #pragma unroll
        for (int r = 0; r < 2; ++r) {
            float4 v = *(const float4*)&featLds[(r0 + r) * FLDA + kk];
            fr[r][0] = v.x; fr[r][1] = v.y; fr[r][2] = v.z; fr[r][3] = v.w;
        }
        #pragma unroll
        for (int q = 0; q < 4; ++q) {
            float4 v = *(const float4*)&sW1[(kk + q) * HDIM + c0];
            wr[q][0] = v.x; wr[q][1] = v.y; wr[q][2] = v.z; wr[q][3] = v.w;
        }
        #pragma unroll
        for (int q = 0; q < 4; ++q)
            #pragma unroll
            for (int r = 0; r < 2; ++r)
                #pragma unroll
                for (int c = 0; c < 4; ++c)
                    acc[r][c] = fmaf(fr[r][q], wr[q][c], acc[r][c]);
    }
    __syncthreads();   // all phase-A reads of sW1/featLds complete

    // ---- repurpose region A: write hLds, stage W2 ----
    #pragma unroll
    for (int r = 0; r < 2; ++r) {
        float4 hv;
        hv.x = fmaxf(acc[r][0], 0.f); hv.y = fmaxf(acc[r][1], 0.f);
        hv.z = fmaxf(acc[r][2], 0.f); hv.w = fmaxf(acc[r][3], 0.f);
        *(float4*)&hLds[(r0 + r) * HLDA + c0] = hv;
    }
    for (int i = t; i < (HDIM * HDIM) / 4; i += 256) {
        float v[4]; load4f<BF16>(W2, (size_t)i * 4, v);
        *(float4*)&sW2[i * 4] = make_float4(v[0], v[1], v[2], v[3]);
    }
    __syncthreads();

    // ---- phase B: reps = h @ W2 + b2 ----
    float acc2[2][4];
    {
        float bb[4]; load4f<BF16>(b2, c0, bb);
        #pragma unroll
        for (int r = 0; r < 2; ++r)
            #pragma unroll
            for (int c = 0; c < 4; ++c) acc2[r][c] = bb[c];
    }
    #pragma unroll 2
    for (int kk = 0; kk < HDIM; kk += 4) {
        float fr[2][4], wr[4][4];
        #pragma unroll
        for (int r = 0; r < 2; ++r) {
            float4 v = *(const float4*)&hLds[(r0 + r) * HLDA + kk];
            fr[r][0] = v.x; fr[r][1] = v.y; fr[r][2] = v.z; fr[r][3] = v.w;
        }
        #pragma unroll
        for (int q = 0; q < 4; ++q) {
            float4 v = *(const float4*)&sW2[(kk + q) * HDIM + c0];
            wr[q][0] = v.x; wr[q][1] = v.y; wr[q][2] = v.z; wr[q][3] = v.w;
        }
        #pragma unroll
        for (int q = 0; q < 4; ++q)
            #pragma unroll
            for (int r = 0; r < 2; ++r)
                #pragma unroll
                for (int c = 0; c < 4; ++c)
                    acc2[r][c] = fmaf(fr[r][q], wr[q][c], acc2[r][c]);
    }

    // ---- write out: f32 reps (d_out) + bf16 reps (ws) ----
    #pragma unroll
    for (int r = 0; r < 2; ++r) {
        int gr = rowBase + r0 + r;           // always < N_NODES (exact grid)
        float4 v;
        v.x = acc2[r][0]; v.y = acc2[r][1]; v.z = acc2[r][2]; v.w = acc2[r][3];
        *(float4*)(out_reps + (size_t)gr * HDIM + c0) = v;
        uint2 pk;
        pk.x = (u32)f_to_bf16(v.x) | ((u32)f_to_bf16(v.y) << 16);
        pk.y = (u32)f_to_bf16(v.z) | ((u32)f_to_bf16(v.w) << 16);
        *(uint2*)(ws_reps + (size_t)gr * HDIM + c0) = pk;
    }
}

// Separate __global__ per specialization (one LDS block, clean regalloc);
// the non-matching one early-exits on the device-side flag.
__global__ void __launch_bounds__(256)
mlp_f32_kernel(const void* __restrict__ feats,
               const void* __restrict__ W1, const void* __restrict__ b1,
               const void* __restrict__ W2, const void* __restrict__ b2,
               float* __restrict__ out_reps, u16* __restrict__ ws_reps,
               const int* __restrict__ flags)
{
    if (flags[0] != 0) return;
    mlp_body<false>(feats, W1, b1, W2, b2, out_reps, ws_reps);
}

__global__ void __launch_bounds__(256)
mlp_bf16_kernel(const void* __restrict__ feats,
                const void* __restrict__ W1, const void* __restrict__ b1,
                const void* __restrict__ W2, const void* __restrict__ b2,
                float* __restrict__ out_reps, u16* __restrict__ ws_reps,
                const int* __restrict__ flags)
{
    if (flags[0] == 0) return;
    mlp_body<true>(feats, W1, b1, W2, b2, out_reps, ws_reps);
}

// ---------------------------------------------------------------------------
// Kernel 2: edge dots from bf16 ws reps (128 B/row = 1 cacheline).
// 8 lanes/edge, exactly E_ORIG*8 threads.
// ---------------------------------------------------------------------------
__global__ void __launch_bounds__(256)
edge_dot_bf16_kernel(const int* __restrict__ eidx,
                     const u16* __restrict__ reps,
                     float* __restrict__ out_pred,
                     const int* __restrict__ flags)
{
    const bool is64 = flags[1] != 0;
    int t = blockIdx.x * 256 + threadIdx.x;
    int e = t >> 3;
    int g = t & 7;
    int s = is64 ? eidx[2 * (size_t)e]            : eidx[e];
    int d = is64 ? eidx[2 * ((size_t)E_ORIG + e)] : eidx[E_ORIG + e];
    uint4 a = *((const uint4*)(reps + (size_t)s * HDIM) + g);
    uint4 b = *((const uint4*)(reps + (size_t)d * HDIM) + g);
    float dot;
    dot = blo(a.x) * blo(b.x);
    dot = fmaf(bhi(a.x), bhi(b.x), dot);
    dot = fmaf(blo(a.y), blo(b.y), dot);
    dot = fmaf(bhi(a.y), bhi(b.y), dot);
    dot = fmaf(blo(a.z), blo(b.z), dot);
    dot = fmaf(bhi(a.z), bhi(b.z), dot);
    dot = fmaf(blo(a.w), blo(b.w), dot);
    dot = fmaf(bhi(a.w), bhi(b.w), dot);
    dot += __shfl_xor(dot, 1);
    dot += __shfl_xor(dot, 2);
    dot += __shfl_xor(dot, 4);
    if (g == 0) out_pred[e] = fmaxf(dot, 0.f);
}

// ---------------------------------------------------------------------------
// Kernel 3: index copies as f32 (bf16-rounded). 4 elems/thread, 16B accesses.
// ---------------------------------------------------------------------------
__global__ void __launch_bounds__(256)
idx_out_kernel(const int* __restrict__ eidx, const int* __restrict__ pidx,
               float* __restrict__ out_tei, float* __restrict__ out_ei,
               const int* __restrict__ flags)
{
    const bool e64 = flags[1] != 0;
    const bool p64 = flags[2] != 0;
    int p = blockIdx.x * 256 + threadIdx.x;
    if (p >= (2 * E_TOT + 2 * E_ORIG) / 4) return;

    const int* src; size_t base; bool s64; float* dst; int o0;
    if (p < (2 * E_TOT) / 4) {
        int i0 = p * 4;
        int row = (i0 >= E_TOT) ? 1 : 0;
        int c = i0 - row * E_TOT;
        if (c < E_ORIG) { src = eidx; base = (size_t)row * E_ORIG + c; s64 = e64; }
        else            { src = pidx; base = (size_t)row * E_CAND + (c - E_ORIG); s64 = p64; }
        dst = out_tei; o0 = i0;
    } else {
        int j0 = (p - (2 * E_TOT) / 4) * 4;
        src = eidx; base = (size_t)j0; s64 = e64; dst = out_ei; o0 = j0;
    }

    int v0, v1, v2, v3;
    if (s64) {
        const long long* s8 = (const long long*)src + base;
        ulonglong2 a = *(const ulonglong2*)s8;
        ulonglong2 b = *((const ulonglong2*)s8 + 1);
        v0 = (int)a.x; v1 = (int)a.y; v2 = (int)b.x; v3 = (int)b.y;
    } else {
        int4 a = *(const int4*)(src + base);
        v0 = a.x; v1 = a.y; v2 = a.z; v3 = a.w;
    }
    float4 o;
    o.x = bf16_round((float)v0); o.y = bf16_round((float)v1);
    o.z = bf16_round((float)v2); o.w = bf16_round((float)v3);
    *(float4*)(dst + o0) = o;
}

extern "C" void kernel_launch(void* const* d_in, const int* in_sizes, int n_in,
                              void* d_out, int out_size, void* d_ws, size_t ws_size,
                              hipStream_t stream) {
    const void* feats = d_in[0];
    const int*  eidx  = (const int*)d_in[1];
    const int*  pidx  = (const int*)d_in[2];
    const void* W1    = d_in[3];
    const void* b1    = d_in[4];
    const void* W2    = d_in[5];
    const void* b2    = d_in[6];

    float* out      = (float*)d_out;
    float* out_reps = out + OFF_REPS;
    float* out_pred = out + OFF_PRED;
    float* out_tei  = out + OFF_TEI;
    float* out_ei   = out + OFF_EI;

    int* flags   = (int*)((char*)d_ws + WS_FLAGS_OFF);
    u16* ws_reps = (u16*)((char*)d_ws + WS_REPS_OFF);

    // 0) dtype detection (1 wave)
    detect_kernel<<<1, 64, 0, stream>>>(feats, eidx, pidx, flags);

    // 1) MLP — both specializations launched; exactly one does the work
    int mlp_blocks = N_NODES / ROWS;             // 3125 (exact)
    mlp_f32_kernel <<<mlp_blocks, 256, 0, stream>>>(feats, W1, b1, W2, b2,
                                                    out_reps, ws_reps, flags);
    mlp_bf16_kernel<<<mlp_blocks, 256, 0, stream>>>(feats, W1, b1, W2, b2,
                                                    out_reps, ws_reps, flags);

    // 2) edge dots for orig edges (bf16 gather, 1 cacheline per row)
    int dot_blocks = (E_ORIG * 8) / 256;         // 50000
    edge_dot_bf16_kernel<<<dot_blocks, 256, 0, stream>>>(eidx, ws_reps, out_pred, flags);

    // 3) index copies
    int idx_packs = (2 * E_TOT + 2 * E_ORIG) / 4;   // 2,000,000
    int idx_blocks = (idx_packs + 255) / 256;       // 7813
    idx_out_kernel<<<idx_blocks, 256, 0, stream>>>(eidx, pidx, out_tei, out_ei, flags);
}

// Round 8
// 196.966 us; speedup vs baseline: 2.0846x; 1.0958x over previous
//
#include <hip/hip_runtime.h>
#include <hip/hip_bf16.h>

#define N_NODES 100000
#define NFEA    128
#define HDIM    64
#define E_ORIG  1600000
#define E_CAND  800000
#define E_TOT   2400000

// flat f32 output offsets (elements), reference return order
#define OFF_REPS 0
#define OFF_PRED 6400000
#define OFF_TEI  8000000
#define OFF_EI   12800000

// workspace layout (bytes)
#define WS_FLAGS_OFF 0
#define WS_REPS_OFF  256
#define WS_REPS_BYTES (N_NODES * HDIM * 2)   // 12.8 MB bf16 reps

// mlp tiling (MFMA)
#define MROWS 64                  // rows per block
#define FS    (NFEA + 8)          // feat / W1^T LDS row stride in bf16 (272 B)
#define HS    (HDIM + 8)          // h / W2^T LDS row stride in bf16 (144 B)

typedef unsigned int u32;
typedef unsigned short u16;
typedef __attribute__((ext_vector_type(8))) short bf16x8;
typedef __attribute__((ext_vector_type(4))) float f32x4;

__device__ __forceinline__ float blo(u32 u) { return __uint_as_float(u << 16); }
__device__ __forceinline__ float bhi(u32 u) { return __uint_as_float(u & 0xFFFF0000u); }

// f32 -> bf16 bits, round-to-nearest-even
__device__ __forceinline__ u16 f_to_bf16(float f) {
    u32 x = __float_as_uint(f);
    return (u16)((x + 0x7FFFu + ((x >> 16) & 1u)) >> 16);
}
__device__ __forceinline__ float bf16_round(float f) {
    return __uint_as_float(((u32)f_to_bf16(f)) << 16);
}

__device__ __forceinline__ void load4f_rt(const void* p, size_t off, bool bf16, float* o) {
    if (bf16) {
        uint2 u = *(const uint2*)((const u16*)p + off);
        o[0] = blo(u.x); o[1] = bhi(u.x); o[2] = blo(u.y); o[3] = bhi(u.y);
    } else {
        float4 v = *(const float4*)((const float*)p + off);
        o[0] = v.x; o[1] = v.y; o[2] = v.z; o[3] = v.w;
    }
}
__device__ __forceinline__ float load1f_rt(const void* p, int idx, bool bf16) {
    if (bf16) return __uint_as_float(((u32)((const u16*)p)[idx]) << 16);
    return ((const float*)p)[idx];
}

// ---------------------------------------------------------------------------
// Kernel 0: dtype detection -> flags in ws.  flags[0]=feats bf16,
// flags[1]=eidx int64, flags[2]=pidx int64.
// ---------------------------------------------------------------------------
__global__ void detect_kernel(const void* __restrict__ feats,
                              const int* __restrict__ eidx,
                              const int* __restrict__ pidx,
                              int* __restrict__ flags)
{
    int lane = threadIdx.x;  // 64 threads
    u32 w = ((const u32*)feats)[lane];
    float lowf = blo(w);
    bool plaus = (lowf == lowf) && (fabsf(lowf) > 0.001f) && (fabsf(lowf) < 64.0f);
    bool isbf16 = __popcll(__ballot(plaus)) >= 32;
    bool e64 = (__ballot(eidx[lane] != 0) & 0xAAAAAAAAAAAAAAAAull) == 0ull;
    bool p64 = (__ballot(pidx[lane] != 0) & 0xAAAAAAAAAAAAAAAAull) == 0ull;
    if (lane == 0) { flags[0] = isbf16; flags[1] = e64; flags[2] = p64; }
}

// ---------------------------------------------------------------------------
// Kernel 1 (MFMA): reps = relu(feat @ W1 + b1) @ W2 + b2.
// 64 rows/block, 256 threads = 4 waves x 16-row strips.
// All operands staged to LDS as bf16 (pad +8 elems -> 2-way conflicts only).
// mfma_f32_16x16x32_bf16; A-frag: row=lane&15, k=(lane>>4)*8+j (16B read);
// B-frag: col=lane&15 (so W stored TRANSPOSED, k contiguous); C/D:
// col=lane&15, row=(lane>>4)*4+reg  [verified mapping].
// Writes f32 reps to d_out and bf16 reps to ws.
// ---------------------------------------------------------------------------
__global__ void __launch_bounds__(256)
mlp_kernel(const void* __restrict__ feats,
           const void* __restrict__ W1, const void* __restrict__ b1,
           const void* __restrict__ W2, const void* __restrict__ b2,
           float* __restrict__ out_reps, u16* __restrict__ ws_reps,
           const int* __restrict__ flags)
{
    __shared__ u16 featLds[MROWS * FS];   // [64][136]  17408 B
    __shared__ u16 w1t[HDIM * FS];        // [64][136]  17408 B (W1^T: [n][k])
    __shared__ u16 hLds[MROWS * HS];      // [64][72]    9216 B
    __shared__ u16 w2t[HDIM * HS];        // [64][72]    9216 B (W2^T: [n][k])

    const bool isbf16 = flags[0] != 0;    // block-uniform branch
    const int t = threadIdx.x;
    const int lane = t & 63;
    const int wv = t >> 6;
    const int rowBase = blockIdx.x * MROWS;

    // ---- stage feats tile -> bf16 LDS (8 iters/thread) ----
    if (isbf16) {
        for (int i = t; i < MROWS * NFEA / 4; i += 256) {
            int r = i >> 5, q = i & 31;
            int gr = rowBase + r;
            uint2 u = make_uint2(0u, 0u);
            if (gr < N_NODES) u = ((const uint2*)feats)[(size_t)gr * 32 + q];
            *(uint2*)&featLds[r * FS + q * 4] = u;
        }
    } else {
        for (int i = t; i < MROWS * NFEA / 4; i += 256) {
            int r = i >> 5, q = i & 31;
            int gr = rowBase + r;
            u32 p0 = 0, p1 = 0;
            if (gr < N_NODES) {
                float4 v = ((const float4*)feats)[(size_t)gr * 32 + q];
                p0 = (u32)f_to_bf16(v.x) | ((u32)f_to_bf16(v.y) << 16);
                p1 = (u32)f_to_bf16(v.z) | ((u32)f_to_bf16(v.w) << 16);
            }
            *(uint2*)&featLds[r * FS + q * 4] = make_uint2(p0, p1);
        }
    }
    // ---- stage W1^T (8/thread) and W2^T (4/thread), transposed scatter ----
    for (int i = t; i < NFEA * HDIM / 4; i += 256) {
        int k = i >> 4, n4 = (i & 15) * 4;
        float v[4]; load4f_rt(W1, (size_t)k * HDIM + n4, isbf16, v);
        #pragma unroll
        for (int j = 0; j < 4; ++j) w1t[(n4 + j) * FS + k] = f_to_bf16(v[j]);
    }
    for (int i = t; i < HDIM * HDIM / 4; i += 256) {
        int k = i >> 4, n4 = (i & 15) * 4;
        float v[4]; load4f_rt(W2, (size_t)k * HDIM + n4, isbf16, v);
        #pragma unroll
        for (int j = 0; j < 4; ++j) w2t[(n4 + j) * HS + k] = f_to_bf16(v[j]);
    }
    __syncthreads();

    const int lm = lane & 15;
    const int lg = lane >> 4;
    const int arow = wv * 16 + lm;        // this lane's A-fragment row

    // ---- phase A: h = relu(feat @ W1 + b1), 16 MFMA/wave ----
    bf16x8 af[4];
    #pragma unroll
    for (int kb = 0; kb < 4; ++kb)
        af[kb] = *(const bf16x8*)&featLds[arow * FS + kb * 32 + lg * 8];

    f32x4 acc[4];
    #pragma unroll
    for (int nt = 0; nt < 4; ++nt) {
        float bv = load1f_rt(b1, nt * 16 + lm, isbf16);
        acc[nt] = (f32x4){bv, bv, bv, bv};
    }
    #pragma unroll
    for (int nt = 0; nt < 4; ++nt) {
        #pragma unroll
        for (int kb = 0; kb < 4; ++kb) {
            bf16x8 bf = *(const bf16x8*)&w1t[(nt * 16 + lm) * FS + kb * 32 + lg * 8];
            acc[nt] = __builtin_amdgcn_mfma_f32_16x16x32_bf16(af[kb], bf, acc[nt], 0, 0, 0);
        }
    }
    // relu -> hLds (bf16). D elem (nt,r) lives at row=(lg*4+r), col=nt*16+lm.
    #pragma unroll
    for (int nt = 0; nt < 4; ++nt)
        #pragma unroll
        for (int r = 0; r < 4; ++r) {
            int row = wv * 16 + lg * 4 + r;
            hLds[row * HS + nt * 16 + lm] = f_to_bf16(fmaxf(acc[nt][r], 0.f));
        }
    __syncthreads();

    // ---- phase B: reps = h @ W2 + b2, 8 MFMA/wave ----
    bf16x8 af2[2];
    #pragma unroll
    for (int kb = 0; kb < 2; ++kb)
        af2[kb] = *(const bf16x8*)&hLds[arow * HS + kb * 32 + lg * 8];

    f32x4 acc2[4];
    #pragma unroll
    for (int nt = 0; nt < 4; ++nt) {
        float bv = load1f_rt(b2, nt * 16 + lm, isbf16);
        acc2[nt] = (f32x4){bv, bv, bv, bv};
    }
    #pragma unroll
    for (int nt = 0; nt < 4; ++nt) {
        #pragma unroll
        for (int kb = 0; kb < 2; ++kb) {
            bf16x8 bf = *(const bf16x8*)&w2t[(nt * 16 + lm) * HS + kb * 32 + lg * 8];
            acc2[nt] = __builtin_amdgcn_mfma_f32_16x16x32_bf16(af2[kb], bf, acc2[nt], 0, 0, 0);
        }
    }

    // ---- write out: f32 reps (d_out) + bf16 reps (ws) ----
    #pragma unroll
    for (int nt = 0; nt < 4; ++nt)
        #pragma unroll
        for (int r = 0; r < 4; ++r) {
            int grow = rowBase + wv * 16 + lg * 4 + r;
            if (grow < N_NODES) {
                int col = nt * 16 + lm;
                float v = acc2[nt][r];
                out_reps[(size_t)grow * HDIM + col] = v;
                ws_reps[(size_t)grow * HDIM + col] = f_to_bf16(v);
            }
        }
}

// ---------------------------------------------------------------------------
// Kernel 2: edge dots from bf16 ws reps (128 B/row = 1 cacheline).
// 8 lanes/edge, exactly E_ORIG*8 threads.
// ---------------------------------------------------------------------------
__global__ void __launch_bounds__(256)
edge_dot_bf16_kernel(const int* __restrict__ eidx,
                     const u16* __restrict__ reps,
                     float* __restrict__ out_pred,
                     const int* __restrict__ flags)
{
    const bool is64 = flags[1] != 0;
    int t = blockIdx.x * 256 + threadIdx.x;
    int e = t >> 3;
    int g = t & 7;
    int s = is64 ? eidx[2 * (size_t)e]            : eidx[e];
    int d = is64 ? eidx[2 * ((size_t)E_ORIG + e)] : eidx[E_ORIG + e];
    uint4 a = *((const uint4*)(reps + (size_t)s * HDIM) + g);
    uint4 b = *((const uint4*)(reps + (size_t)d * HDIM) + g);
    float dot;
    dot = blo(a.x) * blo(b.x);
    dot = fmaf(bhi(a.x), bhi(b.x), dot);
    dot = fmaf(blo(a.y), blo(b.y), dot);
    dot = fmaf(bhi(a.y), bhi(b.y), dot);
    dot = fmaf(blo(a.z), blo(b.z), dot);
    dot = fmaf(bhi(a.z), bhi(b.z), dot);
    dot = fmaf(blo(a.w), blo(b.w), dot);
    dot = fmaf(bhi(a.w), bhi(b.w), dot);
    dot += __shfl_xor(dot, 1);
    dot += __shfl_xor(dot, 2);
    dot += __shfl_xor(dot, 4);
    if (g == 0) out_pred[e] = fmaxf(dot, 0.f);
}

// ---------------------------------------------------------------------------
// Kernel 3: index copies as f32 (bf16-rounded). 4 elems/thread, 16B accesses.
// ---------------------------------------------------------------------------
__global__ void __launch_bounds__(256)
idx_out_kernel(const int* __restrict__ eidx, const int* __restrict__ pidx,
               float* __restrict__ out_tei, float* __restrict__ out_ei,
               const int* __restrict__ flags)
{
    const bool e64 = flags[1] != 0;
    const bool p64 = flags[2] != 0;
    int p = blockIdx.x * 256 + threadIdx.x;
    if (p >= (2 * E_TOT + 2 * E_ORIG) / 4) return;

    const int* src; size_t base; bool s64; float* dst; int o0;
    if (p < (2 * E_TOT) / 4) {
        int i0 = p * 4;
        int row = (i0 >= E_TOT) ? 1 : 0;
        int c = i0 - row * E_TOT;
        if (c < E_ORIG) { src = eidx; base = (size_t)row * E_ORIG + c; s64 = e64; }
        else            { src = pidx; base = (size_t)row * E_CAND + (c - E_ORIG); s64 = p64; }
        dst = out_tei; o0 = i0;
    } else {
        int j0 = (p - (2 * E_TOT) / 4) * 4;
        src = eidx; base = (size_t)j0; s64 = e64; dst = out_ei; o0 = j0;
    }

    int v0, v1, v2, v3;
    if (s64) {
        const long long* s8 = (const long long*)src + base;
        ulonglong2 a = *(const ulonglong2*)s8;
        ulonglong2 b = *((const ulonglong2*)s8 + 1);
        v0 = (int)a.x; v1 = (int)a.y; v2 = (int)b.x; v3 = (int)b.y;
    } else {
        int4 a = *(const int4*)(src + base);
        v0 = a.x; v1 = a.y; v2 = a.z; v3 = a.w;
    }
    float4 o;
    o.x = bf16_round((float)v0); o.y = bf16_round((float)v1);
    o.z = bf16_round((float)v2); o.w = bf16_round((float)v3);
    *(float4*)(dst + o0) = o;
}

extern "C" void kernel_launch(void* const* d_in, const int* in_sizes, int n_in,
                              void* d_out, int out_size, void* d_ws, size_t ws_size,
                              hipStream_t stream) {
    const void* feats = d_in[0];
    const int*  eidx  = (const int*)d_in[1];
    const int*  pidx  = (const int*)d_in[2];
    const void* W1    = d_in[3];
    const void* b1    = d_in[4];
    const void* W2    = d_in[5];
    const void* b2    = d_in[6];

    float* out      = (float*)d_out;
    float* out_reps = out + OFF_REPS;
    float* out_pred = out + OFF_PRED;
    float* out_tei  = out + OFF_TEI;
    float* out_ei   = out + OFF_EI;

    int* flags   = (int*)((char*)d_ws + WS_FLAGS_OFF);
    u16* ws_reps = (u16*)((char*)d_ws + WS_REPS_OFF);

    // 0) dtype detection (1 wave)
    detect_kernel<<<1, 64, 0, stream>>>(feats, eidx, pidx, flags);

    // 1) MLP via MFMA (single kernel; staging branches on device flag)
    int mlp_blocks = (N_NODES + MROWS - 1) / MROWS;   // 1563
    mlp_kernel<<<mlp_blocks, 256, 0, stream>>>(feats, W1, b1, W2, b2,
                                               out_reps, ws_reps, flags);

    // 2) edge dots for orig edges (bf16 gather, 1 cacheline per row)
    int dot_blocks = (E_ORIG * 8) / 256;              // 50000
    edge_dot_bf16_kernel<<<dot_blocks, 256, 0, stream>>>(eidx, ws_reps, out_pred, flags);

    // 3) index copies
    int idx_packs = (2 * E_TOT + 2 * E_ORIG) / 4;     // 2,000,000
    int idx_blocks = (idx_packs + 255) / 256;         // 7813
    idx_out_kernel<<<idx_blocks, 256, 0, stream>>>(eidx, pidx, out_tei, out_ei, flags);
}